// Round 5
// baseline (181.781 us; speedup 1.0000x reference)
//
#include <hip/hip_runtime.h>
#include <cstddef>

// QuadTree attention, 3 levels. B=4, C=128, NHEAD=8, d=16.
// Grids: 16x16 (S=256), 32x32 (S=1024), 64x64 (S=4096). TOPKS=(16,8,8).
//
// R5: KV-interleaved head-major repack (one key = one 128B line with K+V),
// V staged to LDS (transposed, conflict-free) for msg phases, Q head-major
// broadcast loads, XCD-aware block swizzle (id&7 = {b, grid half}).

#define DPP_QUAD_X1 0xB1
#define DPP_QUAD_X2 0x4E
#define DPP_ROR_1   0x121
#define DPP_ROR_2   0x122
#define DPP_ROR_4   0x124
#define DPP_ROR_8   0x128

template<int C>
__device__ __forceinline__ int dpp_i(int x) {
    return __builtin_amdgcn_mov_dpp(x, C, 0xF, 0xF, true);
}
template<int C>
__device__ __forceinline__ float dpp_f(float x) {
    return __int_as_float(__builtin_amdgcn_mov_dpp(__float_as_int(x), C, 0xF, 0xF, true));
}
__device__ __forceinline__ float quadmax4(float x) {
    x = fmaxf(x, dpp_f<DPP_QUAD_X1>(x));
    x = fmaxf(x, dpp_f<DPP_QUAD_X2>(x));
    return x;
}
__device__ __forceinline__ float quadsum4(float x) {
    x += dpp_f<DPP_QUAD_X1>(x);
    x += dpp_f<DPP_QUAD_X2>(x);
    return x;
}
template<int C>
__device__ __forceinline__ void amax_step(float& v, int& s) {
    float ov = dpp_f<C>(v);
    int   os = dpp_i<C>(s);
    const bool take = (ov > v) || (ov == v && os < s);
    v = take ? ov : v;
    s = take ? os : s;
}
__device__ __forceinline__ void amax16(float& v, int& s) {
    amax_step<DPP_ROR_1>(v, s);
    amax_step<DPP_ROR_2>(v, s);
    amax_step<DPP_ROR_4>(v, s);
    amax_step<DPP_ROR_8>(v, s);
}
__device__ __forceinline__ void amax64(float& v, int& s) {
    amax16(v, s);
    {   float ov = __shfl_xor(v, 16); int os = __shfl_xor(s, 16);
        const bool t = (ov > v) || (ov == v && os < s); v = t ? ov : v; s = t ? os : s; }
    {   float ov = __shfl_xor(v, 32); int os = __shfl_xor(s, 32);
        const bool t = (ov > v) || (ov == v && os < s); v = t ? ov : v; s = t ? os : s; }
}
__device__ __forceinline__ float wavemax(float x) {
    x = fmaxf(x, dpp_f<DPP_ROR_1>(x)); x = fmaxf(x, dpp_f<DPP_ROR_2>(x));
    x = fmaxf(x, dpp_f<DPP_ROR_4>(x)); x = fmaxf(x, dpp_f<DPP_ROR_8>(x));
    x = fmaxf(x, __shfl_xor(x, 16));   x = fmaxf(x, __shfl_xor(x, 32));
    return x;
}
__device__ __forceinline__ float wavesum(float x) {
    x += dpp_f<DPP_ROR_1>(x); x += dpp_f<DPP_ROR_2>(x);
    x += dpp_f<DPP_ROR_4>(x); x += dpp_f<DPP_ROR_8>(x);
    x += __shfl_xor(x, 16);   x += __shfl_xor(x, 32);
    return x;
}
__device__ __forceinline__ float dot16(const float* __restrict__ qp, const float* kr) {
    float s = 0.f;
    #pragma unroll
    for (int i = 0; i < 4; ++i) {
        float4 a = *(const float4*)(qp + i*4);
        s = fmaf(a.x, kr[i*4+0], s);
        s = fmaf(a.y, kr[i*4+1], s);
        s = fmaf(a.z, kr[i*4+2], s);
        s = fmaf(a.w, kr[i*4+3], s);
    }
    return s;
}

// ---------------- Repack: head-major Q + KV-interleaved ----------------
// Q:  [b][128][S] -> Qh [b][n][tok][16]
// KV: K,V [b][128][S] -> KV [b][n][tok][32] (k0..15 | v0..15) = 128B/token/head
// grid (60, 8, 4): x<4 Q1(256-tok ck), x<20 Q2(256), x<28 KV1(128), x<60 KV2(128)
__global__ __launch_bounds__(256) void k_repack(
    const float* __restrict__ q1, const float* __restrict__ k1, const float* __restrict__ v1,
    const float* __restrict__ q2, const float* __restrict__ k2, const float* __restrict__ v2,
    float* __restrict__ Q1h, float* __restrict__ KV1,
    float* __restrict__ Q2h, float* __restrict__ KV2)
{
    const int x = blockIdx.x, n = blockIdx.y, b = blockIdx.z;
    const int t = threadIdx.x;
    __shared__ float tA[16][129];
    __shared__ float tB[16][129];

    if (x < 20) {
        const float* src; float* dst; int S, ck;
        if (x < 4) { src = q1; dst = Q1h; S = 1024; ck = x; }
        else       { src = q2; dst = Q2h; S = 4096; ck = x - 4; }
        const int tok0 = ck * 256;
        const float* sp = src + ((size_t)(b*128 + n*16))*S + tok0;
        const int col = t & 127, half = t >> 7;
        #pragma unroll
        for (int j = 0; j < 8; ++j) {
            const int row = j*2 + half;
            tA[row][col] = sp[(size_t)row*S + col];
            tB[row][col] = sp[(size_t)row*S + col + 128];
        }
        __syncthreads();
        float* dp = dst + ((size_t)((b*8 + n)*S) + tok0 + t)*16;
        #pragma unroll
        for (int i = 0; i < 4; ++i) {
            float4 o;
            o.x = (half ? tB : tA)[i*4+0][col];
            o.y = (half ? tB : tA)[i*4+1][col];
            o.z = (half ? tB : tA)[i*4+2][col];
            o.w = (half ? tB : tA)[i*4+3][col];
            *(float4*)(dp + i*4) = o;
        }
    } else {
        const float* sK; const float* sV; float* dst; int S, ck;
        if (x < 28) { sK = k1; sV = v1; dst = KV1; S = 1024; ck = x - 20; }
        else        { sK = k2; sV = v2; dst = KV2; S = 4096; ck = x - 28; }
        const int tok0 = ck * 128;
        const int col = t & 127, rp = t >> 7;
        const float* kp = sK + ((size_t)(b*128 + n*16))*S + tok0;
        const float* vp = sV + ((size_t)(b*128 + n*16))*S + tok0;
        #pragma unroll
        for (int j = 0; j < 8; ++j) {
            const int row = j*2 + rp;
            tA[row][col] = kp[(size_t)row*S + col];
            tB[row][col] = vp[(size_t)row*S + col];
        }
        __syncthreads();
        const int tok = t >> 1, half = t & 1;
        float* dp = dst + (((size_t)((b*8 + n)*S) + tok0 + tok))*32 + half*16;
        #pragma unroll
        for (int i = 0; i < 4; ++i) {
            float4 o;
            o.x = (half ? tB : tA)[i*4+0][tok];
            o.y = (half ? tB : tA)[i*4+1][tok];
            o.z = (half ? tB : tA)[i*4+2][tok];
            o.w = (half ? tB : tA)[i*4+3][tok];
            *(float4*)(dp + i*4) = o;
        }
    }
}

// ---------------- Fused 3-level subtree kernel ----------------
// grid (2048,1,1) x 256; XCD swizzle: id&7 = b + 4*(grid half).
// wave = (b, l0, n). Arena A[640] per wave; V[16][68] = transposed V-stage.
__global__ __launch_bounds__(256) void k_fused(
    const float* __restrict__ q0, const float* __restrict__ k0, const float* __restrict__ v0,
    const float* __restrict__ Q1h, const float* __restrict__ KV1,
    const float* __restrict__ Q2h, const float* __restrict__ KV2,
    float* __restrict__ out)
{
    const int tid = threadIdx.x, lane = tid & 63, wid = tid >> 6;
    const int id  = blockIdx.x;
    const int b   = id & 3;
    const int hh  = (id >> 2) & 1;
    const int loc = id >> 3;                 // 0..255
    const int l0  = hh*128 + (loc & 127);    // 0..255
    const int n   = (loc >> 7)*4 + wid;      // 0..7
    const int H0 = l0 >> 4, W0 = l0 & 15;

    __shared__ float arenaAll[4][640];
    __shared__ float VstAll[4][16][68];
    float* A = arenaAll[wid];
    float (*V)[68] = VstAll[wid];

    // ======== stage A: lvl0 scores (channel-major q0/k0) ========
    const float* qb = q0 + ((size_t)(b*128 + n*16))*256 + l0;
    const float* kb = k0 + ((size_t)(b*128 + n*16))*256 + lane*4;
    float qreg[16];
    #pragma unroll
    for (int dd = 0; dd < 16; ++dd) qreg[dd] = qb[(size_t)dd*256];
    float p[4] = {0.f, 0.f, 0.f, 0.f};
    #pragma unroll
    for (int dd = 0; dd < 16; ++dd) {
        float4 kv = *(const float4*)(kb + (size_t)dd*256);
        p[0] = fmaf(qreg[dd], kv.x, p[0]);
        p[1] = fmaf(qreg[dd], kv.y, p[1]);
        p[2] = fmaf(qreg[dd], kv.z, p[2]);
        p[3] = fmaf(qreg[dd], kv.w, p[3]);
    }
    #pragma unroll
    for (int j = 0; j < 4; ++j) p[j] *= 0.25f;
    float m = fmaxf(fmaxf(p[0], p[1]), fmaxf(p[2], p[3]));
    m = wavemax(m);
    float ls = 0.f;
    #pragma unroll
    for (int j = 0; j < 4; ++j) { p[j] = expf(p[j] - m); ls += p[j]; }
    const float inv = 1.f / wavesum(ls);
    #pragma unroll
    for (int j = 0; j < 4; ++j) p[j] *= inv;

    // ======== stage B: top-16 of 256 ========
    float myv0 = 0.f; int mypos0 = 0;
    #pragma unroll 1
    for (int it = 0; it < 16; ++it) {
        float lv = p[0]; int li = 0;
        if (p[1] > lv) { lv = p[1]; li = 1; }
        if (p[2] > lv) { lv = p[2]; li = 2; }
        if (p[3] > lv) { lv = p[3]; li = 3; }
        int gi = (lane << 2) | li;
        amax64(lv, gi);
        const bool win = (gi >> 2) == lane;
        #pragma unroll
        for (int j = 0; j < 4; ++j)
            p[j] = (win && (gi & 3) == j) ? 0.f : p[j];
        if (lane == it) { myv0 = lv; mypos0 = gi; }
    }

    // ======== stage C: msg0 = masked-p . V0 (channel-major v0) ========
    *(float4*)&A[lane*4 + 4*(lane>>4)] = make_float4(p[0], p[1], p[2], p[3]);
    {
        const int dd = lane & 15, chunk = lane >> 4;
        const float* vb = v0 + ((size_t)(b*128 + n*16 + dd))*256 + chunk*64;
        float acc = 0.f;
        #pragma unroll
        for (int jj = 0; jj < 16; ++jj) {
            float4 vv = *(const float4*)(vb + jj*4);
            float4 pp = *(const float4*)&A[chunk*68 + jj*4];
            acc = fmaf(pp.x, vv.x, acc);
            acc = fmaf(pp.y, vv.y, acc);
            acc = fmaf(pp.z, vv.z, acc);
            acc = fmaf(pp.w, vv.w, acc);
        }
        acc += __shfl_xor(acc, 16);
        acc += __shfl_xor(acc, 32);
        if (lane < 16) A[560 + dd] = acc;
    }

    // ======== stage D: lvl1 scoring (KV 128B gather) + top-8 ========
    const size_t hb1 = (size_t)((b*8 + n)*1024);
    {
        const int kp = lane >> 2, ci = lane & 3;
        const float pscore = __shfl(myv0, kp);
        const int   spos   = __shfl(mypos0, kp);
        const int g1 = (((spos >> 4)*2 + (ci >> 1)) << 5) + ((spos & 15)*2 + (ci & 1));
        const float* kv = KV1 + (hb1 + g1)*32;
        float kr[16];
        #pragma unroll
        for (int i = 0; i < 4; ++i) *(float4*)&kr[i*4] = *(const float4*)(kv + i*4);
        #pragma unroll
        for (int i = 0; i < 4; ++i) {
            float4 vv = *(const float4*)(kv + 16 + i*4);
            V[i*4+0][lane] = vv.x;
            V[i*4+1][lane] = vv.y;
            V[i*4+2][lane] = vv.z;
            V[i*4+3][lane] = vv.w;
        }
        #pragma unroll
        for (int t = 0; t < 4; ++t) {
            const int qtok = ((2*H0 + (t>>1)) << 5) + 2*W0 + (t&1);
            float sc = dot16(Q1h + (hb1 + qtok)*16, kr) * 0.25f;
            const float mm = quadmax4(sc);
            const float e  = expf(sc - mm);
            const float su = quadsum4(e);
            A[288 + t*68 + lane] = (e / su) * pscore;
        }
    }
    float myv1 = 0.f; int myg1 = 0;
    {
        const int tg = lane >> 4, li = lane & 15;
        float p4[4];
        *(float4*)p4 = *(const float4*)&A[288 + tg*68 + li*4];
        int myslot = 0;
        #pragma unroll 1
        for (int it = 0; it < 8; ++it) {
            float bv = p4[0]; int bs = li*4;
            if (p4[1] > bv) { bv = p4[1]; bs = li*4 + 1; }
            if (p4[2] > bv) { bv = p4[2]; bs = li*4 + 2; }
            if (p4[3] > bv) { bv = p4[3]; bs = li*4 + 3; }
            amax16(bv, bs);
            const bool win = (bs >> 2) == li;
            #pragma unroll
            for (int j = 0; j < 4; ++j)
                p4[j] = (win && (bs & 3) == j) ? 0.f : p4[j];
            if (li == it) { myv1 = bv; myslot = bs; }
        }
        *(float4*)&A[288 + tg*68 + li*4] = *(const float4*)p4;   // masked write-back
        const int sp2 = __shfl(mypos0, myslot >> 2);
        const int sci = myslot & 3;
        myg1 = (((sp2 >> 4)*2 + (sci >> 1)) << 5) + ((sp2 & 15)*2 + (sci & 1));
    }

    // ======== stage E: msg1 from LDS (lane = (t,dd), no reduction needed) ==
    {
        const int t = lane >> 4, dd = lane & 15;
        float acc = 0.f;
        #pragma unroll
        for (int kk = 0; kk < 64; ++kk)
            acc = fmaf(A[288 + t*68 + kk], V[dd][kk], acc);
        A[576 + t*16 + dd] = acc;
    }

    // ======== stage F: lvl2 (2 passes of 2 parents) + fusion ========
    const size_t hb2 = (size_t)((b*8 + n)*4096);
    #pragma unroll 1
    for (int hp = 0; hp < 2; ++hp) {
        {
            const int t1l = lane >> 5, kk = lane & 31;
            const int t1 = hp*2 + t1l;
            const int kp2 = kk >> 2, ci2 = kk & 3;
            const float ps1 = __shfl(myv1, t1*16 + kp2);
            const int   g1s = __shfl(myg1, t1*16 + kp2);
            const int g2 = (((g1s >> 5)*2 + (ci2 >> 1)) << 6) + ((g1s & 31)*2 + (ci2 & 1));
            const float* kv = KV2 + (hb2 + g2)*32;
            float kr[16];
            #pragma unroll
            for (int i = 0; i < 4; ++i) *(float4*)&kr[i*4] = *(const float4*)(kv + i*4);
            #pragma unroll
            for (int i = 0; i < 4; ++i) {
                float4 vv = *(const float4*)(kv + 16 + i*4);
                V[i*4+0][lane] = vv.x;     // column = lane = t1l*32+kk
                V[i*4+1][lane] = vv.y;
                V[i*4+2][lane] = vv.z;
                V[i*4+3][lane] = vv.w;
            }
            const int y1 = 2*H0 + (t1 >> 1), x1 = 2*W0 + (t1 & 1);
            #pragma unroll
            for (int t2 = 0; t2 < 4; ++t2) {
                const int qtok2 = ((2*y1 + (t2>>1)) << 6) + 2*x1 + (t2&1);
                float sc = dot16(Q2h + (hb2 + qtok2)*16, kr) * 0.25f;
                const float mm = quadmax4(sc);
                const float e  = expf(sc - mm);
                const float su = quadsum4(e);
                A[t1l*144 + t2*36 + kk] = (e / su) * ps1;
            }
        }
        {
            const int t2 = lane >> 4, dd = lane & 15;
            #pragma unroll
            for (int t1l = 0; t1l < 2; ++t1l) {
                float acc = 0.f;
                #pragma unroll
                for (int kk = 0; kk < 32; ++kk)
                    acc = fmaf(A[t1l*144 + t2*36 + kk], V[dd][t1l*32 + kk], acc);
                const int t1 = hp*2 + t1l;
                A[288 + (t1*4 + t2)*16 + dd] = acc + A[576 + t1*16 + dd] + A[560 + dd];
            }
        }
    }

    // ======== output: channel-major 4x4 patch ========
    {
        const int y = lane & 3, dd = lane >> 2;
        float vr[4];
        #pragma unroll
        for (int x = 0; x < 4; ++x) {
            const int t1 = (((y>>1) << 1) | (x>>1));
            const int t2 = (((y&1)  << 1) | (x&1));
            vr[x] = A[288 + (t1*4 + t2)*16 + dd];
        }
        float* op = out + (((size_t)(b*128 + n*16 + dd)*64 + 4*H0 + y))*64 + 4*W0;
        *(float4*)op = make_float4(vr[0], vr[1], vr[2], vr[3]);
    }
}

extern "C" void kernel_launch(void* const* d_in, const int* in_sizes, int n_in,
                              void* d_out, int out_size, void* d_ws, size_t ws_size,
                              hipStream_t stream)
{
    const float* q0 = (const float*)d_in[0];
    const float* k0 = (const float*)d_in[1];
    const float* v0 = (const float*)d_in[2];
    const float* q1 = (const float*)d_in[3];
    const float* k1 = (const float*)d_in[4];
    const float* v1 = (const float*)d_in[5];
    const float* q2 = (const float*)d_in[6];
    const float* k2 = (const float*)d_in[7];
    const float* v2 = (const float*)d_in[8];

    float* ws  = (float*)d_ws;
    float* Q1h = ws;                 // 4*8*1024*16 = 524288
    float* KV1 = ws + 524288;        // 4*8*1024*32 = 1048576
    float* Q2h = ws + 1572864;       // 4*8*4096*16 = 2097152
    float* KV2 = ws + 3670016;       // 4*8*4096*32 = 4194304

    k_repack<<<dim3(60, 8, 4), 256, 0, stream>>>(q1, k1, v1, q2, k2, v2,
                                                 Q1h, KV1, Q2h, KV2);
    k_fused<<<dim3(2048, 1, 1), 256, 0, stream>>>(q0, k0, v0,
                                                  Q1h, KV1, Q2h, KV2,
                                                  (float*)d_out);
}

// Round 6
// 169.862 us; speedup vs baseline: 1.0702x; 1.0702x over previous
//
#include <hip/hip_runtime.h>
#include <cstddef>

// QuadTree attention, 3 levels. B=4, C=128, NHEAD=8, d=16.
// Grids: 16x16 (S=256), 32x32 (S=1024), 64x64 (S=4096). TOPKS=(16,8,8).
//
// R6: R5's KV-interleaved repack (one key = one 128B line, K|V) kept, but
// V is NOT staged through LDS: msg phases gather V float4s directly from
// global at kv+16 (same line as K score-read -> L1/L2 hot). LDS = arena
// only (10 KB) -> full block residency. Child ids via __shfl recompute.

#define DPP_QUAD_X1 0xB1
#define DPP_QUAD_X2 0x4E
#define DPP_ROR_1   0x121
#define DPP_ROR_2   0x122
#define DPP_ROR_4   0x124
#define DPP_ROR_8   0x128

template<int C>
__device__ __forceinline__ int dpp_i(int x) {
    return __builtin_amdgcn_mov_dpp(x, C, 0xF, 0xF, true);
}
template<int C>
__device__ __forceinline__ float dpp_f(float x) {
    return __int_as_float(__builtin_amdgcn_mov_dpp(__float_as_int(x), C, 0xF, 0xF, true));
}
__device__ __forceinline__ float quadmax4(float x) {
    x = fmaxf(x, dpp_f<DPP_QUAD_X1>(x));
    x = fmaxf(x, dpp_f<DPP_QUAD_X2>(x));
    return x;
}
__device__ __forceinline__ float quadsum4(float x) {
    x += dpp_f<DPP_QUAD_X1>(x);
    x += dpp_f<DPP_QUAD_X2>(x);
    return x;
}
template<int C>
__device__ __forceinline__ void amax_step(float& v, int& s) {
    float ov = dpp_f<C>(v);
    int   os = dpp_i<C>(s);
    const bool take = (ov > v) || (ov == v && os < s);
    v = take ? ov : v;
    s = take ? os : s;
}
__device__ __forceinline__ void amax16(float& v, int& s) {
    amax_step<DPP_ROR_1>(v, s);
    amax_step<DPP_ROR_2>(v, s);
    amax_step<DPP_ROR_4>(v, s);
    amax_step<DPP_ROR_8>(v, s);
}
__device__ __forceinline__ void amax64(float& v, int& s) {
    amax16(v, s);
    {   float ov = __shfl_xor(v, 16); int os = __shfl_xor(s, 16);
        const bool t = (ov > v) || (ov == v && os < s); v = t ? ov : v; s = t ? os : s; }
    {   float ov = __shfl_xor(v, 32); int os = __shfl_xor(s, 32);
        const bool t = (ov > v) || (ov == v && os < s); v = t ? ov : v; s = t ? os : s; }
}
__device__ __forceinline__ float wavemax(float x) {
    x = fmaxf(x, dpp_f<DPP_ROR_1>(x)); x = fmaxf(x, dpp_f<DPP_ROR_2>(x));
    x = fmaxf(x, dpp_f<DPP_ROR_4>(x)); x = fmaxf(x, dpp_f<DPP_ROR_8>(x));
    x = fmaxf(x, __shfl_xor(x, 16));   x = fmaxf(x, __shfl_xor(x, 32));
    return x;
}
__device__ __forceinline__ float wavesum(float x) {
    x += dpp_f<DPP_ROR_1>(x); x += dpp_f<DPP_ROR_2>(x);
    x += dpp_f<DPP_ROR_4>(x); x += dpp_f<DPP_ROR_8>(x);
    x += __shfl_xor(x, 16);   x += __shfl_xor(x, 32);
    return x;
}
__device__ __forceinline__ float dot16(const float* __restrict__ qp, const float* kr) {
    float s = 0.f;
    #pragma unroll
    for (int i = 0; i < 4; ++i) {
        float4 a = *(const float4*)(qp + i*4);
        s = fmaf(a.x, kr[i*4+0], s);
        s = fmaf(a.y, kr[i*4+1], s);
        s = fmaf(a.z, kr[i*4+2], s);
        s = fmaf(a.w, kr[i*4+3], s);
    }
    return s;
}
// child on 32-wide fine grid of coarse key s (16-grid), child c
__device__ __forceinline__ int child32(int s, int c) {
    return (((s >> 4)*2 + (c >> 1)) << 5) + ((s & 15)*2 + (c & 1));
}
// child on 64-wide grid of key g (32-grid), child c
__device__ __forceinline__ int child64(int g, int c) {
    return (((g >> 5)*2 + (c >> 1)) << 6) + ((g & 31)*2 + (c & 1));
}

// ---------------- Repack: head-major Q + KV-interleaved ----------------
// Q:  [b][128][S] -> Qh [b][n][tok][16]
// KV: K,V [b][128][S] -> KV [b][n][tok][32] (k0..15 | v0..15) = 128B/token/head
__global__ __launch_bounds__(256) void k_repack(
    const float* __restrict__ q1, const float* __restrict__ k1, const float* __restrict__ v1,
    const float* __restrict__ q2, const float* __restrict__ k2, const float* __restrict__ v2,
    float* __restrict__ Q1h, float* __restrict__ KV1,
    float* __restrict__ Q2h, float* __restrict__ KV2)
{
    const int x = blockIdx.x, n = blockIdx.y, b = blockIdx.z;
    const int t = threadIdx.x;
    __shared__ float tA[16][129];
    __shared__ float tB[16][129];

    if (x < 20) {
        const float* src; float* dst; int S, ck;
        if (x < 4) { src = q1; dst = Q1h; S = 1024; ck = x; }
        else       { src = q2; dst = Q2h; S = 4096; ck = x - 4; }
        const int tok0 = ck * 256;
        const float* sp = src + ((size_t)(b*128 + n*16))*S + tok0;
        const int col = t & 127, half = t >> 7;
        #pragma unroll
        for (int j = 0; j < 8; ++j) {
            const int row = j*2 + half;
            tA[row][col] = sp[(size_t)row*S + col];
            tB[row][col] = sp[(size_t)row*S + col + 128];
        }
        __syncthreads();
        float* dp = dst + ((size_t)((b*8 + n)*S) + tok0 + t)*16;
        #pragma unroll
        for (int i = 0; i < 4; ++i) {
            float4 o;
            o.x = (half ? tB : tA)[i*4+0][col];
            o.y = (half ? tB : tA)[i*4+1][col];
            o.z = (half ? tB : tA)[i*4+2][col];
            o.w = (half ? tB : tA)[i*4+3][col];
            *(float4*)(dp + i*4) = o;
        }
    } else {
        const float* sK; const float* sV; float* dst; int S, ck;
        if (x < 28) { sK = k1; sV = v1; dst = KV1; S = 1024; ck = x - 20; }
        else        { sK = k2; sV = v2; dst = KV2; S = 4096; ck = x - 28; }
        const int tok0 = ck * 128;
        const int col = t & 127, rp = t >> 7;
        const float* kp = sK + ((size_t)(b*128 + n*16))*S + tok0;
        const float* vp = sV + ((size_t)(b*128 + n*16))*S + tok0;
        #pragma unroll
        for (int j = 0; j < 8; ++j) {
            const int row = j*2 + rp;
            tA[row][col] = kp[(size_t)row*S + col];
            tB[row][col] = vp[(size_t)row*S + col];
        }
        __syncthreads();
        const int tok = t >> 1, half = t & 1;
        float* dp = dst + (((size_t)((b*8 + n)*S) + tok0 + tok))*32 + half*16;
        #pragma unroll
        for (int i = 0; i < 4; ++i) {
            float4 o;
            o.x = (half ? tB : tA)[i*4+0][tok];
            o.y = (half ? tB : tA)[i*4+1][tok];
            o.z = (half ? tB : tA)[i*4+2][tok];
            o.w = (half ? tB : tA)[i*4+3][tok];
            *(float4*)(dp + i*4) = o;
        }
    }
}

// ---------------- Fused 3-level subtree kernel ----------------
// grid (2048,1,1) x 256; XCD swizzle: id&7 = b + 4*(grid half).
// wave = (b, l0, n). Arena A[640] per wave; no V staging.
__global__ __launch_bounds__(256) void k_fused(
    const float* __restrict__ q0, const float* __restrict__ k0, const float* __restrict__ v0,
    const float* __restrict__ Q1h, const float* __restrict__ KV1,
    const float* __restrict__ Q2h, const float* __restrict__ KV2,
    float* __restrict__ out)
{
    const int tid = threadIdx.x, lane = tid & 63, wid = tid >> 6;
    const int id  = blockIdx.x;
    const int b   = id & 3;
    const int hh  = (id >> 2) & 1;
    const int loc = id >> 3;                 // 0..255
    const int l0  = hh*128 + (loc & 127);    // 0..255
    const int n   = (loc >> 7)*4 + wid;      // 0..7
    const int H0 = l0 >> 4, W0 = l0 & 15;

    __shared__ float arenaAll[4][640];
    float* A = arenaAll[wid];

    // ======== stage A: lvl0 scores (channel-major q0/k0) ========
    const float* qb = q0 + ((size_t)(b*128 + n*16))*256 + l0;
    const float* kb = k0 + ((size_t)(b*128 + n*16))*256 + lane*4;
    float qreg[16];
    #pragma unroll
    for (int dd = 0; dd < 16; ++dd) qreg[dd] = qb[(size_t)dd*256];
    float p[4] = {0.f, 0.f, 0.f, 0.f};
    #pragma unroll
    for (int dd = 0; dd < 16; ++dd) {
        float4 kv = *(const float4*)(kb + (size_t)dd*256);
        p[0] = fmaf(qreg[dd], kv.x, p[0]);
        p[1] = fmaf(qreg[dd], kv.y, p[1]);
        p[2] = fmaf(qreg[dd], kv.z, p[2]);
        p[3] = fmaf(qreg[dd], kv.w, p[3]);
    }
    #pragma unroll
    for (int j = 0; j < 4; ++j) p[j] *= 0.25f;
    float m = fmaxf(fmaxf(p[0], p[1]), fmaxf(p[2], p[3]));
    m = wavemax(m);
    float ls = 0.f;
    #pragma unroll
    for (int j = 0; j < 4; ++j) { p[j] = expf(p[j] - m); ls += p[j]; }
    const float inv = 1.f / wavesum(ls);
    #pragma unroll
    for (int j = 0; j < 4; ++j) p[j] *= inv;

    // ======== stage B: top-16 of 256 ========
    float myv0 = 0.f; int mypos0 = 0;
    #pragma unroll 1
    for (int it = 0; it < 16; ++it) {
        float lv = p[0]; int li = 0;
        if (p[1] > lv) { lv = p[1]; li = 1; }
        if (p[2] > lv) { lv = p[2]; li = 2; }
        if (p[3] > lv) { lv = p[3]; li = 3; }
        int gi = (lane << 2) | li;
        amax64(lv, gi);
        const bool win = (gi >> 2) == lane;
        #pragma unroll
        for (int j = 0; j < 4; ++j)
            p[j] = (win && (gi & 3) == j) ? 0.f : p[j];
        if (lane == it) { myv0 = lv; mypos0 = gi; }
    }

    // ======== stage C: msg0 = masked-p . V0 (channel-major v0) ========
    *(float4*)&A[lane*4 + 4*(lane>>4)] = make_float4(p[0], p[1], p[2], p[3]);
    {
        const int dd = lane & 15, chunk = lane >> 4;
        const float* vb = v0 + ((size_t)(b*128 + n*16 + dd))*256 + chunk*64;
        float acc = 0.f;
        #pragma unroll
        for (int jj = 0; jj < 16; ++jj) {
            float4 vv = *(const float4*)(vb + jj*4);
            float4 pp = *(const float4*)&A[chunk*68 + jj*4];
            acc = fmaf(pp.x, vv.x, acc);
            acc = fmaf(pp.y, vv.y, acc);
            acc = fmaf(pp.z, vv.z, acc);
            acc = fmaf(pp.w, vv.w, acc);
        }
        acc += __shfl_xor(acc, 16);
        acc += __shfl_xor(acc, 32);
        if (lane < 16) A[560 + dd] = acc;
    }

    // ======== stage D: lvl1 scoring (KV 128B gather, K half) + top-8 ======
    const size_t hb1 = (size_t)((b*8 + n)*1024);
    {
        const int kp = lane >> 2, ci = lane & 3;
        const float pscore = __shfl(myv0, kp);
        const int   spos   = __shfl(mypos0, kp);
        const int g1 = child32(spos, ci);
        const float* kv = KV1 + (hb1 + g1)*32;
        float kr[16];
        #pragma unroll
        for (int i = 0; i < 4; ++i) *(float4*)&kr[i*4] = *(const float4*)(kv + i*4);
        #pragma unroll
        for (int t = 0; t < 4; ++t) {
            const int qtok = ((2*H0 + (t>>1)) << 5) + 2*W0 + (t&1);
            float sc = dot16(Q1h + (hb1 + qtok)*16, kr) * 0.25f;
            const float mm = quadmax4(sc);
            const float e  = expf(sc - mm);
            const float su = quadsum4(e);
            A[288 + t*68 + lane] = (e / su) * pscore;
        }
    }
    float myv1 = 0.f; int myg1 = 0;
    {
        const int tg = lane >> 4, li = lane & 15;
        float p4[4];
        *(float4*)p4 = *(const float4*)&A[288 + tg*68 + li*4];
        int myslot = 0;
        #pragma unroll 1
        for (int it = 0; it < 8; ++it) {
            float bv = p4[0]; int bs = li*4;
            if (p4[1] > bv) { bv = p4[1]; bs = li*4 + 1; }
            if (p4[2] > bv) { bv = p4[2]; bs = li*4 + 2; }
            if (p4[3] > bv) { bv = p4[3]; bs = li*4 + 3; }
            amax16(bv, bs);
            const bool win = (bs >> 2) == li;
            #pragma unroll
            for (int j = 0; j < 4; ++j)
                p4[j] = (win && (bs & 3) == j) ? 0.f : p4[j];
            if (li == it) { myv1 = bv; myslot = bs; }
        }
        *(float4*)&A[288 + tg*68 + li*4] = *(const float4*)p4;   // masked write-back
        const int sp2 = __shfl(mypos0, myslot >> 2);
        myg1 = child32(sp2, myslot & 3);
    }

    // ======== stage E: msg1 (V gathered from global KV1, L2-hot) ========
    {
        const int ks = lane >> 4, t2 = (lane >> 2) & 3, dq = lane & 3;
        float4 acc = make_float4(0.f, 0.f, 0.f, 0.f);
        #pragma unroll
        for (int jj = 0; jj < 4; ++jj) {
            const int spos_j = __shfl(mypos0, ks*4 + jj);
            float4 pv = *(const float4*)&A[288 + t2*68 + ks*16 + jj*4];
            const float pa[4] = {pv.x, pv.y, pv.z, pv.w};
            #pragma unroll
            for (int c = 0; c < 4; ++c) {
                const int g = child32(spos_j, c);
                float4 vv = *(const float4*)(KV1 + (hb1 + g)*32 + 16 + dq*4);
                acc.x = fmaf(pa[c], vv.x, acc.x);
                acc.y = fmaf(pa[c], vv.y, acc.y);
                acc.z = fmaf(pa[c], vv.z, acc.z);
                acc.w = fmaf(pa[c], vv.w, acc.w);
            }
        }
        acc.x += __shfl_xor(acc.x, 16); acc.y += __shfl_xor(acc.y, 16);
        acc.z += __shfl_xor(acc.z, 16); acc.w += __shfl_xor(acc.w, 16);
        acc.x += __shfl_xor(acc.x, 32); acc.y += __shfl_xor(acc.y, 32);
        acc.z += __shfl_xor(acc.z, 32); acc.w += __shfl_xor(acc.w, 32);
        if (lane < 16)
            *(float4*)&A[576 + t2*16 + dq*4] = acc;
    }

    // ======== stage F: lvl2 (2 passes of 2 parents) + fusion ========
    const size_t hb2 = (size_t)((b*8 + n)*4096);
    #pragma unroll 1
    for (int hp = 0; hp < 2; ++hp) {
        // score: lane = (t1l, kk)
        {
            const int t1l = lane >> 5, kk = lane & 31;
            const int t1 = hp*2 + t1l;
            const int kp2 = kk >> 2, ci2 = kk & 3;
            const float ps1 = __shfl(myv1, t1*16 + kp2);
            const int   g1s = __shfl(myg1, t1*16 + kp2);
            const int g2 = child64(g1s, ci2);
            const float* kv = KV2 + (hb2 + g2)*32;
            float kr[16];
            #pragma unroll
            for (int i = 0; i < 4; ++i) *(float4*)&kr[i*4] = *(const float4*)(kv + i*4);
            const int y1 = 2*H0 + (t1 >> 1), x1 = 2*W0 + (t1 & 1);
            #pragma unroll
            for (int t2 = 0; t2 < 4; ++t2) {
                const int qtok2 = ((2*y1 + (t2>>1)) << 6) + 2*x1 + (t2&1);
                float sc = dot16(Q2h + (hb2 + qtok2)*16, kr) * 0.25f;
                const float mm = quadmax4(sc);
                const float e  = expf(sc - mm);
                const float su = quadsum4(e);
                A[t1l*144 + t2*36 + kk] = (e / su) * ps1;
            }
        }
        // msg: lane = (ks2, qq=(t1l,t2), dq); V from global KV2 (L2-hot)
        {
            const int ks2 = lane >> 5, qq = (lane >> 2) & 7, dq = lane & 3;
            const int t1l = qq >> 2, t2 = qq & 3;
            const int t1 = hp*2 + t1l;
            float4 acc = make_float4(0.f, 0.f, 0.f, 0.f);
            #pragma unroll
            for (int j4 = 0; j4 < 4; ++j4) {
                const int kp2 = ks2*4 + j4;
                const int g1s = __shfl(myg1, t1*16 + kp2);
                float4 pv = *(const float4*)&A[t1l*144 + t2*36 + ks2*16 + j4*4];
                const float pa[4] = {pv.x, pv.y, pv.z, pv.w};
                #pragma unroll
                for (int c = 0; c < 4; ++c) {
                    const int g2 = child64(g1s, c);
                    float4 vv = *(const float4*)(KV2 + (hb2 + g2)*32 + 16 + dq*4);
                    acc.x = fmaf(pa[c], vv.x, acc.x);
                    acc.y = fmaf(pa[c], vv.y, acc.y);
                    acc.z = fmaf(pa[c], vv.z, acc.z);
                    acc.w = fmaf(pa[c], vv.w, acc.w);
                }
            }
            acc.x += __shfl_xor(acc.x, 32); acc.y += __shfl_xor(acc.y, 32);
            acc.z += __shfl_xor(acc.z, 32); acc.w += __shfl_xor(acc.w, 32);
            if (lane < 32) {
                float4 m1 = *(const float4*)&A[576 + t1*16 + dq*4];
                float4 m0 = *(const float4*)&A[560 + dq*4];
                acc.x += m1.x + m0.x;
                acc.y += m1.y + m0.y;
                acc.z += m1.z + m0.z;
                acc.w += m1.w + m0.w;
                *(float4*)&A[288 + (t1*4 + t2)*16 + dq*4] = acc;   // out tile
            }
        }
    }

    // ======== output: channel-major 4x4 patch ========
    {
        const int y = lane & 3, dd = lane >> 2;
        float vr[4];
        #pragma unroll
        for (int x = 0; x < 4; ++x) {
            const int t1 = (((y>>1) << 1) | (x>>1));
            const int t2 = (((y&1)  << 1) | (x&1));
            vr[x] = A[288 + (t1*4 + t2)*16 + dd];
        }
        float* op = out + (((size_t)(b*128 + n*16 + dd)*64 + 4*H0 + y))*64 + 4*W0;
        *(float4*)op = make_float4(vr[0], vr[1], vr[2], vr[3]);
    }
}

extern "C" void kernel_launch(void* const* d_in, const int* in_sizes, int n_in,
                              void* d_out, int out_size, void* d_ws, size_t ws_size,
                              hipStream_t stream)
{
    const float* q0 = (const float*)d_in[0];
    const float* k0 = (const float*)d_in[1];
    const float* v0 = (const float*)d_in[2];
    const float* q1 = (const float*)d_in[3];
    const float* k1 = (const float*)d_in[4];
    const float* v1 = (const float*)d_in[5];
    const float* q2 = (const float*)d_in[6];
    const float* k2 = (const float*)d_in[7];
    const float* v2 = (const float*)d_in[8];

    float* ws  = (float*)d_ws;
    float* Q1h = ws;                 // 4*8*1024*16 = 524288
    float* KV1 = ws + 524288;        // 4*8*1024*32 = 1048576
    float* Q2h = ws + 1572864;       // 4*8*4096*16 = 2097152
    float* KV2 = ws + 3670016;       // 4*8*4096*32 = 4194304

    k_repack<<<dim3(60, 8, 4), 256, 0, stream>>>(q1, k1, v1, q2, k2, v2,
                                                 Q1h, KV1, Q2h, KV2);
    k_fused<<<dim3(2048, 1, 1), 256, 0, stream>>>(q0, k0, v0,
                                                  Q1h, KV1, Q2h, KV2,
                                                  (float*)d_out);
}

// Round 7
// 165.442 us; speedup vs baseline: 1.0988x; 1.0267x over previous
//
#include <hip/hip_runtime.h>
#include <cstddef>

// QuadTree attention, 3 levels. B=4, C=128, NHEAD=8, d=16.
// Grids: 16x16 (S=256), 32x32 (S=1024), 64x64 (S=4096). TOPKS=(16,8,8).
//
// R7: selection rewritten as row-parallel extraction (fusable fmax/min DPP,
// no chained cross-lane LDS) + all-pairs rank merge; winner & child-index
// tables in LDS replace shfl broadcasts and child recomputation.

#define DPP_QUAD_X1 0xB1
#define DPP_QUAD_X2 0x4E
#define DPP_ROR_1   0x121
#define DPP_ROR_2   0x122
#define DPP_ROR_4   0x124
#define DPP_ROR_8   0x128

template<int C>
__device__ __forceinline__ int dpp_i(int x) {
    return __builtin_amdgcn_mov_dpp(x, C, 0xF, 0xF, true);
}
template<int C>
__device__ __forceinline__ float dpp_f(float x) {
    return __int_as_float(__builtin_amdgcn_mov_dpp(__float_as_int(x), C, 0xF, 0xF, true));
}
__device__ __forceinline__ float rowmax16(float x) {
    x = fmaxf(x, dpp_f<DPP_ROR_1>(x));
    x = fmaxf(x, dpp_f<DPP_ROR_2>(x));
    x = fmaxf(x, dpp_f<DPP_ROR_4>(x));
    x = fmaxf(x, dpp_f<DPP_ROR_8>(x));
    return x;
}
__device__ __forceinline__ int rowmin16i(int x) {
    { int o = dpp_i<DPP_ROR_1>(x); x = o < x ? o : x; }
    { int o = dpp_i<DPP_ROR_2>(x); x = o < x ? o : x; }
    { int o = dpp_i<DPP_ROR_4>(x); x = o < x ? o : x; }
    { int o = dpp_i<DPP_ROR_8>(x); x = o < x ? o : x; }
    return x;
}
__device__ __forceinline__ float quadmax4(float x) {
    x = fmaxf(x, dpp_f<DPP_QUAD_X1>(x));
    x = fmaxf(x, dpp_f<DPP_QUAD_X2>(x));
    return x;
}
__device__ __forceinline__ float quadsum4(float x) {
    x += dpp_f<DPP_QUAD_X1>(x);
    x += dpp_f<DPP_QUAD_X2>(x);
    return x;
}
__device__ __forceinline__ float wavemax(float x) {
    x = rowmax16(x);
    x = fmaxf(x, __shfl_xor(x, 16));
    x = fmaxf(x, __shfl_xor(x, 32));
    return x;
}
__device__ __forceinline__ float wavesum(float x) {
    x += dpp_f<DPP_ROR_1>(x); x += dpp_f<DPP_ROR_2>(x);
    x += dpp_f<DPP_ROR_4>(x); x += dpp_f<DPP_ROR_8>(x);
    x += __shfl_xor(x, 16);   x += __shfl_xor(x, 32);
    return x;
}
__device__ __forceinline__ float dot16(const float* __restrict__ qp, const float* kr) {
    float s = 0.f;
    #pragma unroll
    for (int i = 0; i < 4; ++i) {
        float4 a = *(const float4*)(qp + i*4);
        s = fmaf(a.x, kr[i*4+0], s);
        s = fmaf(a.y, kr[i*4+1], s);
        s = fmaf(a.z, kr[i*4+2], s);
        s = fmaf(a.w, kr[i*4+3], s);
    }
    return s;
}
__device__ __forceinline__ int child32(int s, int c) {
    return (((s >> 4)*2 + (c >> 1)) << 5) + ((s & 15)*2 + (c & 1));
}
__device__ __forceinline__ int child64(int g, int c) {
    return (((g >> 5)*2 + (c >> 1)) << 6) + ((g & 31)*2 + (c & 1));
}

// arena layout (floats per wave)
#define W0V  560   // lvl0 winner values  [16]
#define W0P  576   // lvl0 winner pos     [16] (int bits)
#define MSG0 592   // [16]
#define MSG1 608   // [4][16]
#define W1V  672   // lvl1 winner values  [4][8]
#define W1P  704   // lvl1 winner g1      [4][8] (int bits)
#define GT   736   // child-index table   [64] (int bits)
#define ARENA 800

// ---------------- Repack: head-major Q + KV-interleaved ----------------
__global__ __launch_bounds__(256) void k_repack(
    const float* __restrict__ q1, const float* __restrict__ k1, const float* __restrict__ v1,
    const float* __restrict__ q2, const float* __restrict__ k2, const float* __restrict__ v2,
    float* __restrict__ Q1h, float* __restrict__ KV1,
    float* __restrict__ Q2h, float* __restrict__ KV2)
{
    const int x = blockIdx.x, n = blockIdx.y, b = blockIdx.z;
    const int t = threadIdx.x;
    __shared__ float tA[16][129];
    __shared__ float tB[16][129];

    if (x < 20) {
        const float* src; float* dst; int S, ck;
        if (x < 4) { src = q1; dst = Q1h; S = 1024; ck = x; }
        else       { src = q2; dst = Q2h; S = 4096; ck = x - 4; }
        const int tok0 = ck * 256;
        const float* sp = src + ((size_t)(b*128 + n*16))*S + tok0;
        const int col = t & 127, half = t >> 7;
        #pragma unroll
        for (int j = 0; j < 8; ++j) {
            const int row = j*2 + half;
            tA[row][col] = sp[(size_t)row*S + col];
            tB[row][col] = sp[(size_t)row*S + col + 128];
        }
        __syncthreads();
        float* dp = dst + ((size_t)((b*8 + n)*S) + tok0 + t)*16;
        #pragma unroll
        for (int i = 0; i < 4; ++i) {
            float4 o;
            o.x = (half ? tB : tA)[i*4+0][col];
            o.y = (half ? tB : tA)[i*4+1][col];
            o.z = (half ? tB : tA)[i*4+2][col];
            o.w = (half ? tB : tA)[i*4+3][col];
            *(float4*)(dp + i*4) = o;
        }
    } else {
        const float* sK; const float* sV; float* dst; int S, ck;
        if (x < 28) { sK = k1; sV = v1; dst = KV1; S = 1024; ck = x - 20; }
        else        { sK = k2; sV = v2; dst = KV2; S = 4096; ck = x - 28; }
        const int tok0 = ck * 128;
        const int col = t & 127, rp = t >> 7;
        const float* kp = sK + ((size_t)(b*128 + n*16))*S + tok0;
        const float* vp = sV + ((size_t)(b*128 + n*16))*S + tok0;
        #pragma unroll
        for (int j = 0; j < 8; ++j) {
            const int row = j*2 + rp;
            tA[row][col] = kp[(size_t)row*S + col];
            tB[row][col] = vp[(size_t)row*S + col];
        }
        __syncthreads();
        const int tok = t >> 1, half = t & 1;
        float* dp = dst + (((size_t)((b*8 + n)*S) + tok0 + tok))*32 + half*16;
        #pragma unroll
        for (int i = 0; i < 4; ++i) {
            float4 o;
            o.x = (half ? tB : tA)[i*4+0][tok];
            o.y = (half ? tB : tA)[i*4+1][tok];
            o.z = (half ? tB : tA)[i*4+2][tok];
            o.w = (half ? tB : tA)[i*4+3][tok];
            *(float4*)(dp + i*4) = o;
        }
    }
}

// ---------------- Fused 3-level subtree kernel ----------------
__global__ __launch_bounds__(256) void k_fused(
    const float* __restrict__ q0, const float* __restrict__ k0, const float* __restrict__ v0,
    const float* __restrict__ Q1h, const float* __restrict__ KV1,
    const float* __restrict__ Q2h, const float* __restrict__ KV2,
    float* __restrict__ out)
{
    const int tid = threadIdx.x, lane = tid & 63, wid = tid >> 6;
    const int id  = blockIdx.x;
    const int b   = id & 3;
    const int hh  = (id >> 2) & 1;
    const int loc = id >> 3;
    const int l0  = hh*128 + (loc & 127);
    const int n   = (loc >> 7)*4 + wid;
    const int H0 = l0 >> 4, W0 = l0 & 15;

    __shared__ float arenaAll[4][ARENA];
    float* A = arenaAll[wid];

    const float* Q1hh = Q1h + (size_t)((b*8 + n)*1024)*16;
    const float* KV1h = KV1 + (size_t)((b*8 + n)*1024)*32;
    const float* Q2hh = Q2h + (size_t)((b*8 + n)*4096)*16;
    const float* KV2h = KV2 + (size_t)((b*8 + n)*4096)*32;

    // ======== stage A: lvl0 scores + wave softmax ========
    const float* qb = q0 + ((size_t)(b*128 + n*16))*256 + l0;
    const float* kb = k0 + ((size_t)(b*128 + n*16))*256 + lane*4;
    float qreg[16];
    #pragma unroll
    for (int dd = 0; dd < 16; ++dd) qreg[dd] = qb[(size_t)dd*256];
    float p[4] = {0.f, 0.f, 0.f, 0.f};
    #pragma unroll
    for (int dd = 0; dd < 16; ++dd) {
        float4 kv = *(const float4*)(kb + (size_t)dd*256);
        p[0] = fmaf(qreg[dd], kv.x, p[0]);
        p[1] = fmaf(qreg[dd], kv.y, p[1]);
        p[2] = fmaf(qreg[dd], kv.z, p[2]);
        p[3] = fmaf(qreg[dd], kv.w, p[3]);
    }
    #pragma unroll
    for (int j = 0; j < 4; ++j) p[j] *= 0.25f;
    float m = fmaxf(fmaxf(p[0], p[1]), fmaxf(p[2], p[3]));
    m = wavemax(m);
    float ls = 0.f;
    #pragma unroll
    for (int j = 0; j < 4; ++j) { p[j] = expf(p[j] - m); ls += p[j]; }
    const float inv = 1.f / wavesum(ls);
    #pragma unroll
    for (int j = 0; j < 4; ++j) p[j] *= inv;

    const int li = lane & 15;

    // ======== stage B: top-16 of 256 ========
    // phase 1: each 16-lane row extracts its top-16 of its 64 (DPP only)
    float w0 = p[0], w1 = p[1], w2 = p[2], w3 = p[3];
    float cv = 0.f; int cpos = 0;
    #pragma unroll 1
    for (int it = 0; it < 16; ++it) {
        float bv = fmaxf(fmaxf(w0, w1), fmaxf(w2, w3));
        bv = rowmax16(bv);
        int cs = 0x7FFFFFFF;
        cs = (w3 == bv) ? (lane*4 + 3) : cs;
        cs = (w2 == bv) ? (lane*4 + 2) : cs;
        cs = (w1 == bv) ? (lane*4 + 1) : cs;
        cs = (w0 == bv) ? (lane*4 + 0) : cs;
        cs = rowmin16i(cs);
        w0 = (cs == lane*4 + 0) ? 0.f : w0;
        w1 = (cs == lane*4 + 1) ? 0.f : w1;
        w2 = (cs == lane*4 + 2) ? 0.f : w2;
        w3 = (cs == lane*4 + 3) ? 0.f : w3;
        if (li == it) { cv = bv; cpos = cs; }
    }
    // phase 2: rank merge of 64 candidates (broadcast LDS, no chain)
    A[lane]      = cv;
    A[64 + lane] = __int_as_float(cpos);
    *(float4*)&A[288 + lane*4] = make_float4(0.f, 0.f, 0.f, 0.f);   // clear flags
    int rank = 0;
    #pragma unroll
    for (int jj = 0; jj < 16; ++jj) {
        float4 vv = *(const float4*)&A[jj*4];
        float4 pw = *(const float4*)&A[64 + jj*4];
        const int p0i = __float_as_int(pw.x), p1i = __float_as_int(pw.y);
        const int p2i = __float_as_int(pw.z), p3i = __float_as_int(pw.w);
        rank += (vv.x > cv || (vv.x == cv && p0i < cpos)) ? 1 : 0;
        rank += (vv.y > cv || (vv.y == cv && p1i < cpos)) ? 1 : 0;
        rank += (vv.z > cv || (vv.z == cv && p2i < cpos)) ? 1 : 0;
        rank += (vv.w > cv || (vv.w == cv && p3i < cpos)) ? 1 : 0;
    }
    if (rank < 16) {
        A[W0V + rank] = cv;
        A[W0P + rank] = __int_as_float(cpos);
        A[288 + cpos] = 1.0f;                 // mask flag
    }
    {
        float4 f = *(const float4*)&A[288 + lane*4];
        p[0] = (f.x != 0.f) ? 0.f : p[0];
        p[1] = (f.y != 0.f) ? 0.f : p[1];
        p[2] = (f.z != 0.f) ? 0.f : p[2];
        p[3] = (f.w != 0.f) ? 0.f : p[3];
    }
    // chunk-padded masked p for stage C
    *(float4*)&A[lane*4 + 4*(lane>>4)] = make_float4(p[0], p[1], p[2], p[3]);

    // ======== stage C: msg0 = masked-p . V0 ========
    {
        const int dd = lane & 15, chunk = lane >> 4;
        const float* vb = v0 + ((size_t)(b*128 + n*16 + dd))*256 + chunk*64;
        float acc = 0.f;
        #pragma unroll
        for (int jj = 0; jj < 16; ++jj) {
            float4 vv = *(const float4*)(vb + jj*4);
            float4 pp = *(const float4*)&A[chunk*68 + jj*4];
            acc = fmaf(pp.x, vv.x, acc);
            acc = fmaf(pp.y, vv.y, acc);
            acc = fmaf(pp.z, vv.z, acc);
            acc = fmaf(pp.w, vv.w, acc);
        }
        acc += __shfl_xor(acc, 16);
        acc += __shfl_xor(acc, 32);
        if (lane < 16) A[MSG0 + dd] = acc;
    }

    // ======== stage D: lvl1 scoring + top-8 per query ========
    {
        const int kp = lane >> 2, ci = lane & 3;
        const float pscore = A[W0V + kp];
        const int   spos   = __float_as_int(A[W0P + kp]);
        const int g1 = child32(spos, ci);
        A[GT + lane] = __int_as_float(g1);
        const float* kv = KV1h + g1*32;
        float kr[16];
        #pragma unroll
        for (int i = 0; i < 4; ++i) *(float4*)&kr[i*4] = *(const float4*)(kv + i*4);
        #pragma unroll
        for (int t = 0; t < 4; ++t) {
            const int qtok = ((2*H0 + (t>>1)) << 5) + 2*W0 + (t&1);
            float sc = dot16(Q1hh + qtok*16, kr) * 0.25f;
            const float mm = quadmax4(sc);
            const float e  = expf(sc - mm);
            const float su = quadsum4(e);
            A[288 + t*68 + lane] = (e / su) * pscore;
        }
    }
    {
        const int tg = lane >> 4;
        float v0r, v1r, v2r, v3r;
        {
            float4 t4 = *(const float4*)&A[288 + tg*68 + li*4];
            v0r = t4.x; v1r = t4.y; v2r = t4.z; v3r = t4.w;
        }
        float cv1 = 0.f; int cs1 = 0;
        #pragma unroll 1
        for (int it = 0; it < 8; ++it) {
            float bv = fmaxf(fmaxf(v0r, v1r), fmaxf(v2r, v3r));
            bv = rowmax16(bv);
            int cs = 0x7FFFFFFF;
            cs = (v3r == bv) ? (li*4 + 3) : cs;
            cs = (v2r == bv) ? (li*4 + 2) : cs;
            cs = (v1r == bv) ? (li*4 + 1) : cs;
            cs = (v0r == bv) ? (li*4 + 0) : cs;
            cs = rowmin16i(cs);
            v0r = (cs == li*4 + 0) ? 0.f : v0r;
            v1r = (cs == li*4 + 1) ? 0.f : v1r;
            v2r = (cs == li*4 + 2) ? 0.f : v2r;
            v3r = (cs == li*4 + 3) ? 0.f : v3r;
            if (li == it) { cv1 = bv; cs1 = cs; }
        }
        *(float4*)&A[288 + tg*68 + li*4] = make_float4(v0r, v1r, v2r, v3r);  // masked
        if (li < 8) {
            A[W1V + tg*8 + li] = cv1;
            A[W1P + tg*8 + li] = A[GT + cs1];   // g1 of winner key
        }
    }

    // ======== stage E: msg1 (V from global KV1, child ids from GT) ========
    {
        const int ks = lane >> 4, t2 = (lane >> 2) & 3, dq = lane & 3;
        float4 acc = make_float4(0.f, 0.f, 0.f, 0.f);
        #pragma unroll
        for (int jj = 0; jj < 4; ++jj) {
            float4 pv = *(const float4*)&A[288 + t2*68 + ks*16 + jj*4];
            const float pa[4] = {pv.x, pv.y, pv.z, pv.w};
            #pragma unroll
            for (int c = 0; c < 4; ++c) {
                const int g = __float_as_int(A[GT + ks*16 + jj*4 + c]);
                float4 vv = *(const float4*)(KV1h + g*32 + 16 + dq*4);
                acc.x = fmaf(pa[c], vv.x, acc.x);
                acc.y = fmaf(pa[c], vv.y, acc.y);
                acc.z = fmaf(pa[c], vv.z, acc.z);
                acc.w = fmaf(pa[c], vv.w, acc.w);
            }
        }
        acc.x += __shfl_xor(acc.x, 16); acc.y += __shfl_xor(acc.y, 16);
        acc.z += __shfl_xor(acc.z, 16); acc.w += __shfl_xor(acc.w, 16);
        acc.x += __shfl_xor(acc.x, 32); acc.y += __shfl_xor(acc.y, 32);
        acc.z += __shfl_xor(acc.z, 32); acc.w += __shfl_xor(acc.w, 32);
        if (lane < 16)
            *(float4*)&A[MSG1 + t2*16 + dq*4] = acc;
    }

    // ======== stage F: lvl2 (2 passes of 2 parents) + fusion ========
    #pragma unroll 1
    for (int hp = 0; hp < 2; ++hp) {
        {
            const int t1l = lane >> 5, kk = lane & 31;
            const int t1 = hp*2 + t1l;
            const int kp2 = kk >> 2, ci2 = kk & 3;
            const float ps1 = A[W1V + t1*8 + kp2];
            const int   g1s = __float_as_int(A[W1P + t1*8 + kp2]);
            const int g2 = child64(g1s, ci2);
            A[GT + t1l*32 + kk] = __int_as_float(g2);
            const float* kv = KV2h + g2*32;
            float kr[16];
            #pragma unroll
            for (int i = 0; i < 4; ++i) *(float4*)&kr[i*4] = *(const float4*)(kv + i*4);
            const int y1 = 2*H0 + (t1 >> 1), x1 = 2*W0 + (t1 & 1);
            #pragma unroll
            for (int t2 = 0; t2 < 4; ++t2) {
                const int qtok2 = ((2*y1 + (t2>>1)) << 6) + 2*x1 + (t2&1);
                float sc = dot16(Q2hh + qtok2*16, kr) * 0.25f;
                const float mm = quadmax4(sc);
                const float e  = expf(sc - mm);
                const float su = quadsum4(e);
                A[t1l*144 + t2*36 + kk] = (e / su) * ps1;
            }
        }
        {
            const int ks2 = lane >> 5, qq = (lane >> 2) & 7, dq = lane & 3;
            const int t1l = qq >> 2, t2 = qq & 3;
            const int t1 = hp*2 + t1l;
            float4 acc = make_float4(0.f, 0.f, 0.f, 0.f);
            #pragma unroll
            for (int j4 = 0; j4 < 4; ++j4) {
                float4 pv = *(const float4*)&A[t1l*144 + t2*36 + ks2*16 + j4*4];
                const float pa[4] = {pv.x, pv.y, pv.z, pv.w};
                #pragma unroll
                for (int c = 0; c < 4; ++c) {
                    const int g2 = __float_as_int(A[GT + t1l*32 + ks2*16 + j4*4 + c]);
                    float4 vv = *(const float4*)(KV2h + g2*32 + 16 + dq*4);
                    acc.x = fmaf(pa[c], vv.x, acc.x);
                    acc.y = fmaf(pa[c], vv.y, acc.y);
                    acc.z = fmaf(pa[c], vv.z, acc.z);
                    acc.w = fmaf(pa[c], vv.w, acc.w);
                }
            }
            acc.x += __shfl_xor(acc.x, 32); acc.y += __shfl_xor(acc.y, 32);
            acc.z += __shfl_xor(acc.z, 32); acc.w += __shfl_xor(acc.w, 32);
            if (lane < 32) {
                float4 m1 = *(const float4*)&A[MSG1 + t1*16 + dq*4];
                float4 m0 = *(const float4*)&A[MSG0 + dq*4];
                acc.x += m1.x + m0.x;
                acc.y += m1.y + m0.y;
                acc.z += m1.z + m0.z;
                acc.w += m1.w + m0.w;
                *(float4*)&A[288 + (t1*4 + t2)*16 + dq*4] = acc;   // out tile
            }
        }
    }

    // ======== output: channel-major 4x4 patch ========
    {
        const int y = lane & 3, dd = lane >> 2;
        float vr[4];
        #pragma unroll
        for (int x = 0; x < 4; ++x) {
            const int t1 = (((y>>1) << 1) | (x>>1));
            const int t2 = (((y&1)  << 1) | (x&1));
            vr[x] = A[288 + (t1*4 + t2)*16 + dd];
        }
        float* op = out + (((size_t)(b*128 + n*16 + dd)*64 + 4*H0 + y))*64 + 4*W0;
        *(float4*)op = make_float4(vr[0], vr[1], vr[2], vr[3]);
    }
}

extern "C" void kernel_launch(void* const* d_in, const int* in_sizes, int n_in,
                              void* d_out, int out_size, void* d_ws, size_t ws_size,
                              hipStream_t stream)
{
    const float* q0 = (const float*)d_in[0];
    const float* k0 = (const float*)d_in[1];
    const float* v0 = (const float*)d_in[2];
    const float* q1 = (const float*)d_in[3];
    const float* k1 = (const float*)d_in[4];
    const float* v1 = (const float*)d_in[5];
    const float* q2 = (const float*)d_in[6];
    const float* k2 = (const float*)d_in[7];
    const float* v2 = (const float*)d_in[8];

    float* ws  = (float*)d_ws;
    float* Q1h = ws;                 // 4*8*1024*16 = 524288
    float* KV1 = ws + 524288;        // 4*8*1024*32 = 1048576
    float* Q2h = ws + 1572864;       // 4*8*4096*16 = 2097152
    float* KV2 = ws + 3670016;       // 4*8*4096*32 = 4194304

    k_repack<<<dim3(60, 8, 4), 256, 0, stream>>>(q1, k1, v1, q2, k2, v2,
                                                 Q1h, KV1, Q2h, KV2);
    k_fused<<<dim3(2048, 1, 1), 256, 0, stream>>>(q0, k0, v0,
                                                  Q1h, KV1, Q2h, KV2,
                                                  (float*)d_out);
}